// Round 6
// baseline (294.360 us; speedup 1.0000x reference)
//
#include <hip/hip_runtime.h>
#include <hip/hip_bf16.h>
#include <math.h>

// B=4, T=128, S=512, D=512. Outputs: attn_h (4,128,512) then align (4,128,512), fp32.
// Single persistent kernel, 3 phases separated by device-scope grid barriers:
//   P1: Ew=exp(2(inp@Wq^T+bq)), Eu=exp(2 ctx@Wc^T), GT=(WL@ctx^T) bf16,
//       Y0=inp@WR^T+bout                              (640 GEMM tiles)
//   P2: Sraw[b,t,s] = V - 2*sum_d v/(1+Ew*Eu)         (4096 tiles)
//   P3: row-softmax(Sraw) fused; attn = P@GT^T + Y0; align_vectors out (64 tiles)

typedef __attribute__((ext_vector_type(8))) short short8;
typedef __attribute__((ext_vector_type(4))) float f32x4;
typedef unsigned short ushort_t;

static __device__ __forceinline__ unsigned short f2bf(float x) {
    union { __hip_bfloat16 h; unsigned short u; } c;
    c.h = __float2bfloat16(x);
    return c.u;
}
static __device__ __forceinline__ int bf2x(float lo, float hi) {
    return (int)(((unsigned)f2bf(hi) << 16) | (unsigned)f2bf(lo));
}

template<bool BF>
static __device__ __forceinline__ void load16(const void* base, size_t elemoff,
                                              int4& r0, int4& r1) {
    if (BF) {
        const int4* p = (const int4*)((const ushort_t*)base + elemoff);
        r0 = p[0]; r1 = p[1];
    } else {
        const float4* p = (const float4*)((const float*)base + elemoff);
        float4 a = p[0], b = p[1], c = p[2], d = p[3];
        r0.x = bf2x(a.x, a.y); r0.y = bf2x(a.z, a.w);
        r0.z = bf2x(b.x, b.y); r0.w = bf2x(b.z, b.w);
        r1.x = bf2x(c.x, c.y); r1.y = bf2x(c.z, c.w);
        r1.z = bf2x(d.x, d.y); r1.w = bf2x(d.z, d.w);
    }
}

// ---------------------------------------------------------------------------
// MFMA NT GEMM tile: C[m,n] = sum_k A[m,k]*W[n,k] (+bias). 64x64 tile, BK=64.
// EPI: 0 = fp32 (+bias); 1 = fp32 exp(2*(x+bias)); 2 = bf16.
// ---------------------------------------------------------------------------
template<bool A_BF, bool W_BF, int EPI>
static __device__ __forceinline__ void gemm_body(
    ushort_t* As, ushort_t* Ws,
    const void* A, const void* W, const float* bias,
    void* Cv, int K, int lda, int ldw, int ldc, int bm, int bn)
{
    const int tid = threadIdx.x;
    const int wave = tid >> 6, lane = tid & 63;
    const int mh = (wave & 1) * 32, nh = (wave >> 1) * 32;
    const int quad = lane >> 4, l16 = lane & 15;
    const int srow = tid >> 2, schunk = tid & 3;

    const size_t aoff = (size_t)(bm + srow) * lda + schunk * 16;
    const size_t woff = (size_t)(bn + srow) * ldw + schunk * 16;
    int4* AsW = (int4*)&As[srow * 72 + schunk * 16];
    int4* WsW = (int4*)&Ws[srow * 72 + schunk * 16];

    f32x4 acc00 = {0.f, 0.f, 0.f, 0.f}, acc01 = acc00, acc10 = acc00, acc11 = acc00;

    int4 a0r, a1r, w0r, w1r;
    load16<A_BF>(A, aoff, a0r, a1r);
    load16<W_BF>(W, woff, w0r, w1r);

    for (int k0 = 0; k0 < K; k0 += 64) {
        __syncthreads();            // protect LDS reuse across tiles/phases
        AsW[0] = a0r; AsW[1] = a1r;
        WsW[0] = w0r; WsW[1] = w1r;
        __syncthreads();
        if (k0 + 64 < K) {
            load16<A_BF>(A, aoff + k0 + 64, a0r, a1r);
            load16<W_BF>(W, woff + k0 + 64, w0r, w1r);
        }
        #pragma unroll
        for (int kk = 0; kk < 64; kk += 32) {
            short8 a0 = *(const short8*)&As[(mh + l16) * 72 + kk + quad * 8];
            short8 a1 = *(const short8*)&As[(mh + 16 + l16) * 72 + kk + quad * 8];
            short8 b0 = *(const short8*)&Ws[(nh + l16) * 72 + kk + quad * 8];
            short8 b1 = *(const short8*)&Ws[(nh + 16 + l16) * 72 + kk + quad * 8];
            acc00 = __builtin_amdgcn_mfma_f32_16x16x32_bf16(a0, b0, acc00, 0, 0, 0);
            acc01 = __builtin_amdgcn_mfma_f32_16x16x32_bf16(a0, b1, acc01, 0, 0, 0);
            acc10 = __builtin_amdgcn_mfma_f32_16x16x32_bf16(a1, b0, acc10, 0, 0, 0);
            acc11 = __builtin_amdgcn_mfma_f32_16x16x32_bf16(a1, b1, acc11, 0, 0, 0);
        }
    }

    const int col0 = bn + nh + l16;
    const int col1 = col0 + 16;
    float bias0 = bias ? bias[col0] : 0.f;
    float bias1 = bias ? bias[col1] : 0.f;

    f32x4 accs[2][2] = {{acc00, acc01}, {acc10, acc11}};
    #pragma unroll
    for (int mt = 0; mt < 2; ++mt) {
        #pragma unroll
        for (int r = 0; r < 4; ++r) {
            int row = bm + mh + mt * 16 + quad * 4 + r;
            size_t rowoff = (size_t)row * ldc;
            float v0 = accs[mt][0][r] + bias0;
            float v1 = accs[mt][1][r] + bias1;
            if (EPI == 1) { v0 = __expf(2.f * v0); v1 = __expf(2.f * v1); }
            if (EPI == 2) {
                ushort_t* C = (ushort_t*)Cv;
                C[rowoff + col0] = f2bf(v0);
                C[rowoff + col1] = f2bf(v1);
            } else {
                float* C = (float*)Cv;
                C[rowoff + col0] = v0;
                C[rowoff + col1] = v1;
            }
        }
    }
}

// ---------------------------------------------------------------------------
// Phase 1 tile dispatch (640 tiles)
// ---------------------------------------------------------------------------
static __device__ __forceinline__ void front_tile(
    int t, ushort_t* As, ushort_t* Ws,
    const float* inp, const float* ctx, const float* Wq, const float* bq,
    const float* Wc, const float* Wout, const float* bout,
    float* Ew, float* Eu, float* Y0, ushort_t* GT)
{
    if (t < 64) {
        gemm_body<false, false, 1>(As, Ws, inp, Wq, bq, Ew,
                                   512, 512, 512, 512, (t & 7) * 64, (t >> 3) * 64);
    } else if (t < 320) {
        int i = t - 64;
        gemm_body<false, false, 1>(As, Ws, ctx, Wc, nullptr, Eu,
                                   512, 512, 512, 512, (i & 31) * 64, (i >> 5) * 64);
    } else if (t < 576) {
        int i = t - 320;
        int b = i >> 6, j = i & 63;
        gemm_body<false, false, 2>(As, Ws, Wout, ctx + (size_t)b * 262144, nullptr,
                                   GT + (size_t)b * 262144,
                                   512, 1024, 512, 512, (j & 7) * 64, (j >> 3) * 64);
    } else {
        int i = t - 576;
        gemm_body<false, false, 0>(As, Ws, inp, Wout + 512, bout, Y0,
                                   512, 512, 1024, 512, (i & 7) * 64, (i >> 3) * 64);
    }
}

// ---------------------------------------------------------------------------
// Phase 2 tile: Sraw[b,t,s] = V - 2*sum_d v[d]/(1+Ew*Eu). idx in [0,4096).
// ---------------------------------------------------------------------------
static __device__ __forceinline__ void align_tile(
    int idx, const float* Ew, const float* Eu, const float* v, float* out)
{
    const int lane = threadIdx.x & 63, wave = threadIdx.x >> 6;
    const int sx = idx & 63;
    const int ty = (idx >> 6) & 15;
    const int b  = idx >> 10;
    const int t0 = ty * 8 + wave * 2;
    const int s0 = sx * 8;

    const float* w0p = Ew + (((size_t)(b * 128 + t0)) << 9);
    const float* w1p = w0p + 512;
    const float* up  = Eu + (((size_t)(b * 512 + s0)) << 9);

    float acc0[8], acc1[8];
    #pragma unroll
    for (int j = 0; j < 8; ++j) { acc0[j] = 0.f; acc1[j] = 0.f; }
    float vsum = 0.f;

    for (int k0 = 0; k0 < 512; k0 += 64) {
        float vk = v[k0 + lane];
        vsum += vk;
        float w0 = w0p[k0 + lane];
        float w1 = w1p[k0 + lane];
        #pragma unroll
        for (int j = 0; j < 8; ++j) {
            float u = up[((size_t)j << 9) + k0 + lane];
            float d0 = fmaf(w0, u, 1.f);
            float d1 = fmaf(w1, u, 1.f);
            float r0 = __builtin_amdgcn_rcpf(d0);
            float r1 = __builtin_amdgcn_rcpf(d1);
            acc0[j] = fmaf(vk, r0, acc0[j]);
            acc1[j] = fmaf(vk, r1, acc1[j]);
        }
    }

    float V = vsum;
    #pragma unroll
    for (int off = 32; off; off >>= 1) V += __shfl_xor(V, off, 64);

    float r0 = 0.f, r1 = 0.f;
    #pragma unroll
    for (int j = 0; j < 8; ++j) {
        float a = acc0[j], c = acc1[j];
        #pragma unroll
        for (int off = 32; off; off >>= 1) {
            a += __shfl_xor(a, off, 64);
            c += __shfl_xor(c, off, 64);
        }
        if (lane == j) { r0 = fmaf(-2.f, a, V); r1 = fmaf(-2.f, c, V); }
    }
    if (lane < 8) {
        size_t o = (((size_t)(b * 128 + t0)) << 9) + s0 + lane;
        out[o] = r0;
        out[o + 512] = r1;
    }
}

// ---------------------------------------------------------------------------
// Phase 3 tile: softmax fused into A-staging; attn = P@GT^T + Y0. idx in [0,64).
// by==0 tiles also write softmaxed fp32 align rows.
// ---------------------------------------------------------------------------
static __device__ __forceinline__ void att_tile(
    int idx, ushort_t* As, ushort_t* Ws,
    const float* Sraw, const ushort_t* GT, const float* Y0,
    float* attn, float* alignv)
{
    const int bx = idx & 1, by = (idx >> 1) & 7, b = idx >> 4;
    const int tid = threadIdx.x;
    const int bm = bx * 64, bn = by * 64;
    const int wave = tid >> 6, lane = tid & 63;
    const int mh = (wave & 1) * 32, nh = (wave >> 1) * 32;
    const int quad = lane >> 4, l16 = lane & 15;
    const int srow = tid >> 2, schunk = tid & 3;

    const float* Srow = Sraw + (((size_t)(b * 128 + bm + srow)) << 9);

    const float4* qv = (const float4*)(Srow + schunk * 128);
    float mloc = -3.4e38f;
    #pragma unroll
    for (int i = 0; i < 32; ++i) {
        float4 x = qv[i];
        mloc = fmaxf(mloc, fmaxf(fmaxf(x.x, x.y), fmaxf(x.z, x.w)));
    }
    mloc = fmaxf(mloc, __shfl_xor(mloc, 1, 64));
    mloc = fmaxf(mloc, __shfl_xor(mloc, 2, 64));
    float ssum = 0.f;
    #pragma unroll
    for (int i = 0; i < 32; ++i) {
        float4 x = qv[i];
        ssum += __expf(x.x - mloc) + __expf(x.y - mloc)
              + __expf(x.z - mloc) + __expf(x.w - mloc);
    }
    ssum += __shfl_xor(ssum, 1, 64);
    ssum += __shfl_xor(ssum, 2, 64);
    const float rinv = __builtin_amdgcn_rcpf(ssum);

    const bool wr = (by == 0);
    float* arow = alignv + (((size_t)(b * 128 + bm + srow)) << 9);
    const ushort_t* GTb = GT + (size_t)b * 262144;
    const size_t woff = (size_t)(bn + srow) * 512 + schunk * 16;
    int4* AsW = (int4*)&As[srow * 72 + schunk * 16];
    int4* WsW = (int4*)&Ws[srow * 72 + schunk * 16];

    f32x4 acc00 = {0.f, 0.f, 0.f, 0.f}, acc01 = acc00, acc10 = acc00, acc11 = acc00;

    for (int k0 = 0; k0 < 512; k0 += 64) {
        const float4* ap = (const float4*)(Srow + k0 + schunk * 16);
        float4 x0 = ap[0], x1 = ap[1], x2 = ap[2], x3 = ap[3];
        float4 p0, p1, p2, p3;
        p0.x = __expf(x0.x - mloc) * rinv; p0.y = __expf(x0.y - mloc) * rinv;
        p0.z = __expf(x0.z - mloc) * rinv; p0.w = __expf(x0.w - mloc) * rinv;
        p1.x = __expf(x1.x - mloc) * rinv; p1.y = __expf(x1.y - mloc) * rinv;
        p1.z = __expf(x1.z - mloc) * rinv; p1.w = __expf(x1.w - mloc) * rinv;
        p2.x = __expf(x2.x - mloc) * rinv; p2.y = __expf(x2.y - mloc) * rinv;
        p2.z = __expf(x2.z - mloc) * rinv; p2.w = __expf(x2.w - mloc) * rinv;
        p3.x = __expf(x3.x - mloc) * rinv; p3.y = __expf(x3.y - mloc) * rinv;
        p3.z = __expf(x3.z - mloc) * rinv; p3.w = __expf(x3.w - mloc) * rinv;
        int4 w0r, w1r;
        load16<true>(GTb, woff + k0, w0r, w1r);
        if (wr) {
            float4* d = (float4*)(arow + k0 + schunk * 16);
            d[0] = p0; d[1] = p1; d[2] = p2; d[3] = p3;
        }
        int4 a0r, a1r;
        a0r.x = bf2x(p0.x, p0.y); a0r.y = bf2x(p0.z, p0.w);
        a0r.z = bf2x(p1.x, p1.y); a0r.w = bf2x(p1.z, p1.w);
        a1r.x = bf2x(p2.x, p2.y); a1r.y = bf2x(p2.z, p2.w);
        a1r.z = bf2x(p3.x, p3.y); a1r.w = bf2x(p3.z, p3.w);
        __syncthreads();
        AsW[0] = a0r; AsW[1] = a1r;
        WsW[0] = w0r; WsW[1] = w1r;
        __syncthreads();
        #pragma unroll
        for (int kk = 0; kk < 64; kk += 32) {
            short8 a0 = *(const short8*)&As[(mh + l16) * 72 + kk + quad * 8];
            short8 a1 = *(const short8*)&As[(mh + 16 + l16) * 72 + kk + quad * 8];
            short8 b0 = *(const short8*)&Ws[(nh + l16) * 72 + kk + quad * 8];
            short8 b1 = *(const short8*)&Ws[(nh + 16 + l16) * 72 + kk + quad * 8];
            acc00 = __builtin_amdgcn_mfma_f32_16x16x32_bf16(a0, b0, acc00, 0, 0, 0);
            acc01 = __builtin_amdgcn_mfma_f32_16x16x32_bf16(a0, b1, acc01, 0, 0, 0);
            acc10 = __builtin_amdgcn_mfma_f32_16x16x32_bf16(a1, b0, acc10, 0, 0, 0);
            acc11 = __builtin_amdgcn_mfma_f32_16x16x32_bf16(a1, b1, acc11, 0, 0, 0);
        }
    }

    const int col0 = bn + nh + l16;
    const int col1 = col0 + 16;
    f32x4 accs[2][2] = {{acc00, acc01}, {acc10, acc11}};
    #pragma unroll
    for (int mt = 0; mt < 2; ++mt) {
        #pragma unroll
        for (int r = 0; r < 4; ++r) {
            size_t rowoff = (size_t)(b * 128 + bm + mh + mt * 16 + quad * 4 + r) << 9;
            attn[rowoff + col0] = accs[mt][0][r] + Y0[rowoff + col0];
            attn[rowoff + col1] = accs[mt][1][r] + Y0[rowoff + col1];
        }
    }
}

// ---------------------------------------------------------------------------
// Device-scope grid barrier: monotonic counter, arrive + spin.
// ---------------------------------------------------------------------------
static __device__ __forceinline__ void grid_barrier(int* bar, int target) {
    __syncthreads();
    if (threadIdx.x == 0) {
        __threadfence();    // make prior global writes visible device-wide
        __hip_atomic_fetch_add(bar, 1, __ATOMIC_ACQ_REL, __HIP_MEMORY_SCOPE_AGENT);
        while (__hip_atomic_load(bar, __ATOMIC_ACQUIRE, __HIP_MEMORY_SCOPE_AGENT) < target)
            __builtin_amdgcn_s_sleep(2);
        __threadfence();
    }
    __syncthreads();
}

// ---------------------------------------------------------------------------
__global__ __launch_bounds__(256, 4) void mega(
    const float* __restrict__ inp, const float* __restrict__ ctx,
    const float* __restrict__ Wq, const float* __restrict__ bq,
    const float* __restrict__ Wc, const float* __restrict__ v,
    const float* __restrict__ Wout, const float* __restrict__ bout,
    float* __restrict__ Ew, float* __restrict__ Eu, float* __restrict__ Y0,
    ushort_t* __restrict__ GT, float* __restrict__ Sraw,
    float* __restrict__ attn, float* __restrict__ alignv, int* bar)
{
    __shared__ ushort_t As[64 * 72];
    __shared__ ushort_t Ws[64 * 72];
    const int nblk = gridDim.x;

    for (int t = blockIdx.x; t < 640; t += nblk)
        front_tile(t, As, Ws, inp, ctx, Wq, bq, Wc, Wout, bout, Ew, Eu, Y0, GT);

    grid_barrier(bar, nblk);

    for (int i = blockIdx.x; i < 4096; i += nblk)
        align_tile(i, Ew, Eu, v, Sraw);

    grid_barrier(bar, 2 * nblk);

    for (int i = blockIdx.x; i < 64; i += nblk)
        att_tile(i, As, Ws, Sraw, GT, Y0, attn, alignv);
}

// ---------------------------------------------------------------------------
extern "C" void kernel_launch(void* const* d_in, const int* in_sizes, int n_in,
                              void* d_out, int out_size, void* d_ws, size_t ws_size,
                              hipStream_t stream)
{
    const float* inp  = (const float*)d_in[0];   // (4,128,512)
    const float* ctx  = (const float*)d_in[1];   // (4,512,512)
    const float* Wq   = (const float*)d_in[2];   // (512,512)
    const float* bq   = (const float*)d_in[3];   // (512)
    const float* Wc   = (const float*)d_in[4];   // (512,512)
    const float* v    = (const float*)d_in[5];   // (512)
    const float* Wout = (const float*)d_in[6];   // (512,1024)
    const float* bout = (const float*)d_in[7];   // (512)

    float* out    = (float*)d_out;
    float* attn   = out;              // 262144 floats
    float* alignv = out + 262144;     // 262144 floats

    float* ws = (float*)d_ws;
    float* Ew   = ws;                          // 262144 f
    float* Eu   = ws + 262144;                 // 1048576 f
    float* Y0   = ws + 1310720;                // 262144 f
    float* Sraw = ws + 1572864;                // 262144 f
    ushort_t* GT = (ushort_t*)(ws + 1835008);  // 4 x 262144 u16 = 524288 f
    int* bar = (int*)(ws + 2359296);           // barrier counter (256 B zone)

    // Co-residency: grid = CUs x resident-blocks/CU (pure host query, capture-safe).
    int maxB = 1;
    if (hipOccupancyMaxActiveBlocksPerMultiprocessor(&maxB, mega, 256, 0) != hipSuccess
        || maxB < 1)
        maxB = 1;
    if (maxB > 4) maxB = 4;
    int nblk = 256 * maxB;

    hipMemsetAsync(bar, 0, 256, stream);
    mega<<<dim3(nblk), 256, 0, stream>>>(inp, ctx, Wq, bq, Wc, v, Wout, bout,
                                         Ew, Eu, Y0, GT, Sraw, attn, alignv, bar);
}

// Round 7
// 202.933 us; speedup vs baseline: 1.4505x; 1.4505x over previous
//
#include <hip/hip_runtime.h>
#include <hip/hip_bf16.h>
#include <math.h>

// B=4, T=128, S=512, D=512. Outputs: attn_h (4,128,512) then align (4,128,512), fp32.
// Single persistent kernel, 3 phases separated by device-scope grid barriers:
//   P1: Ew=exp(2(inp@Wq^T+bq)), Eu=exp(2 ctx@Wc^T), GT=(WL@ctx^T) bf16,
//       Y0=inp@WR^T+bout                              (640 GEMM tiles)
//   P2: Sraw[b,t,s] = V - 2*sum_d v/(1+Ew*Eu)         (4096 tiles)
//   P3: row-softmax(Sraw) fused; attn = P@GT^T + Y0; align_vectors out (64 tiles)
// Barrier: RELEASE arrive + RELAXED spin + single ACQUIRE on exit. (R6 bug:
// acquire-per-spin-iteration -> buffer_inv per poll -> L2 thrash, 430 us.)

typedef __attribute__((ext_vector_type(8))) short short8;
typedef __attribute__((ext_vector_type(4))) float f32x4;
typedef unsigned short ushort_t;

static __device__ __forceinline__ unsigned short f2bf(float x) {
    union { __hip_bfloat16 h; unsigned short u; } c;
    c.h = __float2bfloat16(x);
    return c.u;
}
static __device__ __forceinline__ int bf2x(float lo, float hi) {
    return (int)(((unsigned)f2bf(hi) << 16) | (unsigned)f2bf(lo));
}

template<bool BF>
static __device__ __forceinline__ void load16(const void* base, size_t elemoff,
                                              int4& r0, int4& r1) {
    if (BF) {
        const int4* p = (const int4*)((const ushort_t*)base + elemoff);
        r0 = p[0]; r1 = p[1];
    } else {
        const float4* p = (const float4*)((const float*)base + elemoff);
        float4 a = p[0], b = p[1], c = p[2], d = p[3];
        r0.x = bf2x(a.x, a.y); r0.y = bf2x(a.z, a.w);
        r0.z = bf2x(b.x, b.y); r0.w = bf2x(b.z, b.w);
        r1.x = bf2x(c.x, c.y); r1.y = bf2x(c.z, c.w);
        r1.z = bf2x(d.x, d.y); r1.w = bf2x(d.z, d.w);
    }
}

// ---------------------------------------------------------------------------
// MFMA NT GEMM tile: C[m,n] = sum_k A[m,k]*W[n,k] (+bias). 64x64 tile, BK=64.
// EPI: 0 = fp32 (+bias); 1 = fp32 exp(2*(x+bias)); 2 = bf16.
// ---------------------------------------------------------------------------
template<bool A_BF, bool W_BF, int EPI>
static __device__ __forceinline__ void gemm_body(
    ushort_t* As, ushort_t* Ws,
    const void* A, const void* W, const float* bias,
    void* Cv, int K, int lda, int ldw, int ldc, int bm, int bn)
{
    const int tid = threadIdx.x;
    const int wave = tid >> 6, lane = tid & 63;
    const int mh = (wave & 1) * 32, nh = (wave >> 1) * 32;
    const int quad = lane >> 4, l16 = lane & 15;
    const int srow = tid >> 2, schunk = tid & 3;

    const size_t aoff = (size_t)(bm + srow) * lda + schunk * 16;
    const size_t woff = (size_t)(bn + srow) * ldw + schunk * 16;
    int4* AsW = (int4*)&As[srow * 72 + schunk * 16];
    int4* WsW = (int4*)&Ws[srow * 72 + schunk * 16];

    f32x4 acc00 = {0.f, 0.f, 0.f, 0.f}, acc01 = acc00, acc10 = acc00, acc11 = acc00;

    int4 a0r, a1r, w0r, w1r;
    load16<A_BF>(A, aoff, a0r, a1r);
    load16<W_BF>(W, woff, w0r, w1r);

    for (int k0 = 0; k0 < K; k0 += 64) {
        __syncthreads();            // protect LDS reuse across tiles/phases
        AsW[0] = a0r; AsW[1] = a1r;
        WsW[0] = w0r; WsW[1] = w1r;
        __syncthreads();
        if (k0 + 64 < K) {
            load16<A_BF>(A, aoff + k0 + 64, a0r, a1r);
            load16<W_BF>(W, woff + k0 + 64, w0r, w1r);
        }
        #pragma unroll
        for (int kk = 0; kk < 64; kk += 32) {
            short8 a0 = *(const short8*)&As[(mh + l16) * 72 + kk + quad * 8];
            short8 a1 = *(const short8*)&As[(mh + 16 + l16) * 72 + kk + quad * 8];
            short8 b0 = *(const short8*)&Ws[(nh + l16) * 72 + kk + quad * 8];
            short8 b1 = *(const short8*)&Ws[(nh + 16 + l16) * 72 + kk + quad * 8];
            acc00 = __builtin_amdgcn_mfma_f32_16x16x32_bf16(a0, b0, acc00, 0, 0, 0);
            acc01 = __builtin_amdgcn_mfma_f32_16x16x32_bf16(a0, b1, acc01, 0, 0, 0);
            acc10 = __builtin_amdgcn_mfma_f32_16x16x32_bf16(a1, b0, acc10, 0, 0, 0);
            acc11 = __builtin_amdgcn_mfma_f32_16x16x32_bf16(a1, b1, acc11, 0, 0, 0);
        }
    }

    const int col0 = bn + nh + l16;
    const int col1 = col0 + 16;
    float bias0 = bias ? bias[col0] : 0.f;
    float bias1 = bias ? bias[col1] : 0.f;

    f32x4 accs[2][2] = {{acc00, acc01}, {acc10, acc11}};
    #pragma unroll
    for (int mt = 0; mt < 2; ++mt) {
        #pragma unroll
        for (int r = 0; r < 4; ++r) {
            int row = bm + mh + mt * 16 + quad * 4 + r;
            size_t rowoff = (size_t)row * ldc;
            float v0 = accs[mt][0][r] + bias0;
            float v1 = accs[mt][1][r] + bias1;
            if (EPI == 1) { v0 = __expf(2.f * v0); v1 = __expf(2.f * v1); }
            if (EPI == 2) {
                ushort_t* C = (ushort_t*)Cv;
                C[rowoff + col0] = f2bf(v0);
                C[rowoff + col1] = f2bf(v1);
            } else {
                float* C = (float*)Cv;
                C[rowoff + col0] = v0;
                C[rowoff + col1] = v1;
            }
        }
    }
}

// ---------------------------------------------------------------------------
// Phase 1 tile dispatch (640 tiles)
// ---------------------------------------------------------------------------
static __device__ __forceinline__ void front_tile(
    int t, ushort_t* As, ushort_t* Ws,
    const float* inp, const float* ctx, const float* Wq, const float* bq,
    const float* Wc, const float* Wout, const float* bout,
    float* Ew, float* Eu, float* Y0, ushort_t* GT)
{
    if (t < 64) {
        gemm_body<false, false, 1>(As, Ws, inp, Wq, bq, Ew,
                                   512, 512, 512, 512, (t & 7) * 64, (t >> 3) * 64);
    } else if (t < 320) {
        int i = t - 64;
        gemm_body<false, false, 1>(As, Ws, ctx, Wc, nullptr, Eu,
                                   512, 512, 512, 512, (i & 31) * 64, (i >> 5) * 64);
    } else if (t < 576) {
        int i = t - 320;
        int b = i >> 6, j = i & 63;
        gemm_body<false, false, 2>(As, Ws, Wout, ctx + (size_t)b * 262144, nullptr,
                                   GT + (size_t)b * 262144,
                                   512, 1024, 512, 512, (j & 7) * 64, (j >> 3) * 64);
    } else {
        int i = t - 576;
        gemm_body<false, false, 0>(As, Ws, inp, Wout + 512, bout, Y0,
                                   512, 512, 1024, 512, (i & 7) * 64, (i >> 3) * 64);
    }
}

// ---------------------------------------------------------------------------
// Phase 2 tile: Sraw[b,t,s] = V - 2*sum_d v[d]/(1+Ew*Eu). idx in [0,4096).
// ---------------------------------------------------------------------------
static __device__ __forceinline__ void align_tile(
    int idx, const float* Ew, const float* Eu, const float* v, float* out)
{
    const int lane = threadIdx.x & 63, wave = threadIdx.x >> 6;
    const int sx = idx & 63;
    const int ty = (idx >> 6) & 15;
    const int b  = idx >> 10;
    const int t0 = ty * 8 + wave * 2;
    const int s0 = sx * 8;

    const float* w0p = Ew + (((size_t)(b * 128 + t0)) << 9);
    const float* w1p = w0p + 512;
    const float* up  = Eu + (((size_t)(b * 512 + s0)) << 9);

    float acc0[8], acc1[8];
    #pragma unroll
    for (int j = 0; j < 8; ++j) { acc0[j] = 0.f; acc1[j] = 0.f; }
    float vsum = 0.f;

    for (int k0 = 0; k0 < 512; k0 += 64) {
        float vk = v[k0 + lane];
        vsum += vk;
        float w0 = w0p[k0 + lane];
        float w1 = w1p[k0 + lane];
        #pragma unroll
        for (int j = 0; j < 8; ++j) {
            float u = up[((size_t)j << 9) + k0 + lane];
            float d0 = fmaf(w0, u, 1.f);
            float d1 = fmaf(w1, u, 1.f);
            float r0 = __builtin_amdgcn_rcpf(d0);
            float r1 = __builtin_amdgcn_rcpf(d1);
            acc0[j] = fmaf(vk, r0, acc0[j]);
            acc1[j] = fmaf(vk, r1, acc1[j]);
        }
    }

    float V = vsum;
    #pragma unroll
    for (int off = 32; off; off >>= 1) V += __shfl_xor(V, off, 64);

    float r0 = 0.f, r1 = 0.f;
    #pragma unroll
    for (int j = 0; j < 8; ++j) {
        float a = acc0[j], c = acc1[j];
        #pragma unroll
        for (int off = 32; off; off >>= 1) {
            a += __shfl_xor(a, off, 64);
            c += __shfl_xor(c, off, 64);
        }
        if (lane == j) { r0 = fmaf(-2.f, a, V); r1 = fmaf(-2.f, c, V); }
    }
    if (lane < 8) {
        size_t o = (((size_t)(b * 128 + t0)) << 9) + s0 + lane;
        out[o] = r0;
        out[o + 512] = r1;
    }
}

// ---------------------------------------------------------------------------
// Phase 3 tile: softmax fused into A-staging; attn = P@GT^T + Y0. idx in [0,64).
// by==0 tiles also write softmaxed fp32 align rows.
// ---------------------------------------------------------------------------
static __device__ __forceinline__ void att_tile(
    int idx, ushort_t* As, ushort_t* Ws,
    const float* Sraw, const ushort_t* GT, const float* Y0,
    float* attn, float* alignv)
{
    const int bx = idx & 1, by = (idx >> 1) & 7, b = idx >> 4;
    const int tid = threadIdx.x;
    const int bm = bx * 64, bn = by * 64;
    const int wave = tid >> 6, lane = tid & 63;
    const int mh = (wave & 1) * 32, nh = (wave >> 1) * 32;
    const int quad = lane >> 4, l16 = lane & 15;
    const int srow = tid >> 2, schunk = tid & 3;

    const float* Srow = Sraw + (((size_t)(b * 128 + bm + srow)) << 9);

    const float4* qv = (const float4*)(Srow + schunk * 128);
    float mloc = -3.4e38f;
    #pragma unroll
    for (int i = 0; i < 32; ++i) {
        float4 x = qv[i];
        mloc = fmaxf(mloc, fmaxf(fmaxf(x.x, x.y), fmaxf(x.z, x.w)));
    }
    mloc = fmaxf(mloc, __shfl_xor(mloc, 1, 64));
    mloc = fmaxf(mloc, __shfl_xor(mloc, 2, 64));
    float ssum = 0.f;
    #pragma unroll
    for (int i = 0; i < 32; ++i) {
        float4 x = qv[i];
        ssum += __expf(x.x - mloc) + __expf(x.y - mloc)
              + __expf(x.z - mloc) + __expf(x.w - mloc);
    }
    ssum += __shfl_xor(ssum, 1, 64);
    ssum += __shfl_xor(ssum, 2, 64);
    const float rinv = __builtin_amdgcn_rcpf(ssum);

    const bool wr = (by == 0);
    float* arow = alignv + (((size_t)(b * 128 + bm + srow)) << 9);
    const ushort_t* GTb = GT + (size_t)b * 262144;
    const size_t woff = (size_t)(bn + srow) * 512 + schunk * 16;
    int4* AsW = (int4*)&As[srow * 72 + schunk * 16];
    int4* WsW = (int4*)&Ws[srow * 72 + schunk * 16];

    f32x4 acc00 = {0.f, 0.f, 0.f, 0.f}, acc01 = acc00, acc10 = acc00, acc11 = acc00;

    for (int k0 = 0; k0 < 512; k0 += 64) {
        const float4* ap = (const float4*)(Srow + k0 + schunk * 16);
        float4 x0 = ap[0], x1 = ap[1], x2 = ap[2], x3 = ap[3];
        float4 p0, p1, p2, p3;
        p0.x = __expf(x0.x - mloc) * rinv; p0.y = __expf(x0.y - mloc) * rinv;
        p0.z = __expf(x0.z - mloc) * rinv; p0.w = __expf(x0.w - mloc) * rinv;
        p1.x = __expf(x1.x - mloc) * rinv; p1.y = __expf(x1.y - mloc) * rinv;
        p1.z = __expf(x1.z - mloc) * rinv; p1.w = __expf(x1.w - mloc) * rinv;
        p2.x = __expf(x2.x - mloc) * rinv; p2.y = __expf(x2.y - mloc) * rinv;
        p2.z = __expf(x2.z - mloc) * rinv; p2.w = __expf(x2.w - mloc) * rinv;
        p3.x = __expf(x3.x - mloc) * rinv; p3.y = __expf(x3.y - mloc) * rinv;
        p3.z = __expf(x3.z - mloc) * rinv; p3.w = __expf(x3.w - mloc) * rinv;
        int4 w0r, w1r;
        load16<true>(GTb, woff + k0, w0r, w1r);
        if (wr) {
            float4* d = (float4*)(arow + k0 + schunk * 16);
            d[0] = p0; d[1] = p1; d[2] = p2; d[3] = p3;
        }
        int4 a0r, a1r;
        a0r.x = bf2x(p0.x, p0.y); a0r.y = bf2x(p0.z, p0.w);
        a0r.z = bf2x(p1.x, p1.y); a0r.w = bf2x(p1.z, p1.w);
        a1r.x = bf2x(p2.x, p2.y); a1r.y = bf2x(p2.z, p2.w);
        a1r.z = bf2x(p3.x, p3.y); a1r.w = bf2x(p3.z, p3.w);
        __syncthreads();
        AsW[0] = a0r; AsW[1] = a1r;
        WsW[0] = w0r; WsW[1] = w1r;
        __syncthreads();
        #pragma unroll
        for (int kk = 0; kk < 64; kk += 32) {
            short8 a0 = *(const short8*)&As[(mh + l16) * 72 + kk + quad * 8];
            short8 a1 = *(const short8*)&As[(mh + 16 + l16) * 72 + kk + quad * 8];
            short8 b0 = *(const short8*)&Ws[(nh + l16) * 72 + kk + quad * 8];
            short8 b1 = *(const short8*)&Ws[(nh + 16 + l16) * 72 + kk + quad * 8];
            acc00 = __builtin_amdgcn_mfma_f32_16x16x32_bf16(a0, b0, acc00, 0, 0, 0);
            acc01 = __builtin_amdgcn_mfma_f32_16x16x32_bf16(a0, b1, acc01, 0, 0, 0);
            acc10 = __builtin_amdgcn_mfma_f32_16x16x32_bf16(a1, b0, acc10, 0, 0, 0);
            acc11 = __builtin_amdgcn_mfma_f32_16x16x32_bf16(a1, b1, acc11, 0, 0, 0);
        }
    }

    const int col0 = bn + nh + l16;
    const int col1 = col0 + 16;
    f32x4 accs[2][2] = {{acc00, acc01}, {acc10, acc11}};
    #pragma unroll
    for (int mt = 0; mt < 2; ++mt) {
        #pragma unroll
        for (int r = 0; r < 4; ++r) {
            size_t rowoff = (size_t)(b * 128 + bm + mh + mt * 16 + quad * 4 + r) << 9;
            attn[rowoff + col0] = accs[mt][0][r] + Y0[rowoff + col0];
            attn[rowoff + col1] = accs[mt][1][r] + Y0[rowoff + col1];
        }
    }
}

// ---------------------------------------------------------------------------
// Device-scope grid barrier. Arrive with RELEASE add (one L2-wb per block),
// spin on RELAXED load (sc1 read, NO cache invalidate), single ACQUIRE load
// after exit (one buffer_inv per block). s_sleep(16) keeps poll rate low.
// ---------------------------------------------------------------------------
static __device__ __forceinline__ void grid_barrier(int* bar, int target) {
    __syncthreads();
    if (threadIdx.x == 0) {
        __hip_atomic_fetch_add(bar, 1, __ATOMIC_RELEASE, __HIP_MEMORY_SCOPE_AGENT);
        while (__hip_atomic_load(bar, __ATOMIC_RELAXED, __HIP_MEMORY_SCOPE_AGENT) < target)
            __builtin_amdgcn_s_sleep(16);
        (void)__hip_atomic_load(bar, __ATOMIC_ACQUIRE, __HIP_MEMORY_SCOPE_AGENT);
    }
    __syncthreads();
}

// ---------------------------------------------------------------------------
__global__ __launch_bounds__(256, 4) void mega(
    const float* __restrict__ inp, const float* __restrict__ ctx,
    const float* __restrict__ Wq, const float* __restrict__ bq,
    const float* __restrict__ Wc, const float* __restrict__ v,
    const float* __restrict__ Wout, const float* __restrict__ bout,
    float* __restrict__ Ew, float* __restrict__ Eu, float* __restrict__ Y0,
    ushort_t* __restrict__ GT, float* __restrict__ Sraw,
    float* __restrict__ attn, float* __restrict__ alignv, int* bar)
{
    __shared__ ushort_t As[64 * 72];
    __shared__ ushort_t Ws[64 * 72];
    const int nblk = gridDim.x;

    for (int t = blockIdx.x; t < 640; t += nblk)
        front_tile(t, As, Ws, inp, ctx, Wq, bq, Wc, Wout, bout, Ew, Eu, Y0, GT);

    grid_barrier(bar, nblk);

    for (int i = blockIdx.x; i < 4096; i += nblk)
        align_tile(i, Ew, Eu, v, Sraw);

    grid_barrier(bar, 2 * nblk);

    for (int i = blockIdx.x; i < 64; i += nblk)
        att_tile(i, As, Ws, Sraw, GT, Y0, attn, alignv);
}

// ---------------------------------------------------------------------------
extern "C" void kernel_launch(void* const* d_in, const int* in_sizes, int n_in,
                              void* d_out, int out_size, void* d_ws, size_t ws_size,
                              hipStream_t stream)
{
    const float* inp  = (const float*)d_in[0];   // (4,128,512)
    const float* ctx  = (const float*)d_in[1];   // (4,512,512)
    const float* Wq   = (const float*)d_in[2];   // (512,512)
    const float* bq   = (const float*)d_in[3];   // (512)
    const float* Wc   = (const float*)d_in[4];   // (512,512)
    const float* v    = (const float*)d_in[5];   // (512)
    const float* Wout = (const float*)d_in[6];   // (512,1024)
    const float* bout = (const float*)d_in[7];   // (512)

    float* out    = (float*)d_out;
    float* attn   = out;              // 262144 floats
    float* alignv = out + 262144;     // 262144 floats

    float* ws = (float*)d_ws;
    float* Ew   = ws;                          // 262144 f
    float* Eu   = ws + 262144;                 // 1048576 f
    float* Y0   = ws + 1310720;                // 262144 f
    float* Sraw = ws + 1572864;                // 262144 f
    ushort_t* GT = (ushort_t*)(ws + 1835008);  // 4 x 262144 u16 = 524288 f
    int* bar = (int*)(ws + 2359296);           // barrier counter (256 B zone)

    // Co-residency: grid = CUs x resident-blocks/CU (pure host query, capture-safe).
    int maxB = 1;
    if (hipOccupancyMaxActiveBlocksPerMultiprocessor(&maxB, mega, 256, 0) != hipSuccess
        || maxB < 1)
        maxB = 1;
    if (maxB > 4) maxB = 4;
    int nblk = 256 * maxB;

    hipMemsetAsync(bar, 0, 256, stream);
    mega<<<dim3(nblk), 256, 0, stream>>>(inp, ctx, Wq, bq, Wc, v, Wout, bout,
                                         Ew, Eu, Y0, GT, Sraw, attn, alignv, bar);
}

// Round 8
// 180.553 us; speedup vs baseline: 1.6303x; 1.1240x over previous
//
#include <hip/hip_runtime.h>
#include <hip/hip_bf16.h>
#include <math.h>

// B=4, T=128, S=512, D=512. Outputs: attn_h (4,128,512) then align (4,128,512), fp32.
// 2-kernel pipeline:
//   K1 fused_front (640 blocks): Ew=exp(2(inp@Wq^T+bq)), Eu=exp(2 ctx@Wc^T),
//      GT[b]=(WL@ctx_b^T) bf16, Y0=inp@WR^T+bout
//   K2 fused_align (512 blocks, one (b,t) row each):
//      scores s = V - 2*sum_d v/(1+Ew*Eu)  (== sum_d v*tanh(wq+uh))
//      -> block softmax (exp once per element) -> alignv out
//      -> attn row = P @ GT^T + Y0  (fp32 P x bf16 GT, shuffle-reduced dots)

typedef __attribute__((ext_vector_type(8))) short short8;
typedef __attribute__((ext_vector_type(4))) float f32x4;
typedef unsigned short ushort_t;

static __device__ __forceinline__ unsigned short f2bf(float x) {
    union { __hip_bfloat16 h; unsigned short u; } c;
    c.h = __float2bfloat16(x);
    return c.u;
}
static __device__ __forceinline__ int bf2x(float lo, float hi) {
    return (int)(((unsigned)f2bf(hi) << 16) | (unsigned)f2bf(lo));
}
static __device__ __forceinline__ float bfu_as_f(unsigned u) {
    union { unsigned u; float f; } c; c.u = u; return c.f;
}

template<bool BF>
static __device__ __forceinline__ void load16(const void* base, size_t elemoff,
                                              int4& r0, int4& r1) {
    if (BF) {
        const int4* p = (const int4*)((const ushort_t*)base + elemoff);
        r0 = p[0]; r1 = p[1];
    } else {
        const float4* p = (const float4*)((const float*)base + elemoff);
        float4 a = p[0], b = p[1], c = p[2], d = p[3];
        r0.x = bf2x(a.x, a.y); r0.y = bf2x(a.z, a.w);
        r0.z = bf2x(b.x, b.y); r0.w = bf2x(b.z, b.w);
        r1.x = bf2x(c.x, c.y); r1.y = bf2x(c.z, c.w);
        r1.z = bf2x(d.x, d.y); r1.w = bf2x(d.z, d.w);
    }
}

// ---------------------------------------------------------------------------
// MFMA NT GEMM tile: C[m,n] = sum_k A[m,k]*W[n,k] (+bias). 64x64 tile, BK=64,
// 256 thr = 4 waves (2x2 of 32x32), 2x2 MFMA 16x16x32 per 32-K step.
// LDS rows padded to 72 bf16. EPI: 0 fp32+bias; 1 fp32 exp(2*(x+bias)); 2 bf16.
// ---------------------------------------------------------------------------
template<bool A_BF, bool W_BF, int EPI>
static __device__ __forceinline__ void gemm_body(
    ushort_t* As, ushort_t* Ws,
    const void* A, const void* W, const float* bias,
    void* Cv, int K, int lda, int ldw, int ldc, int bm, int bn)
{
    const int tid = threadIdx.x;
    const int wave = tid >> 6, lane = tid & 63;
    const int mh = (wave & 1) * 32, nh = (wave >> 1) * 32;
    const int quad = lane >> 4, l16 = lane & 15;
    const int srow = tid >> 2, schunk = tid & 3;

    const size_t aoff = (size_t)(bm + srow) * lda + schunk * 16;
    const size_t woff = (size_t)(bn + srow) * ldw + schunk * 16;
    int4* AsW = (int4*)&As[srow * 72 + schunk * 16];
    int4* WsW = (int4*)&Ws[srow * 72 + schunk * 16];

    f32x4 acc00 = {0.f, 0.f, 0.f, 0.f}, acc01 = acc00, acc10 = acc00, acc11 = acc00;

    int4 a0r, a1r, w0r, w1r;
    load16<A_BF>(A, aoff, a0r, a1r);
    load16<W_BF>(W, woff, w0r, w1r);

    for (int k0 = 0; k0 < K; k0 += 64) {
        AsW[0] = a0r; AsW[1] = a1r;
        WsW[0] = w0r; WsW[1] = w1r;
        __syncthreads();
        if (k0 + 64 < K) {
            load16<A_BF>(A, aoff + k0 + 64, a0r, a1r);
            load16<W_BF>(W, woff + k0 + 64, w0r, w1r);
        }
        #pragma unroll
        for (int kk = 0; kk < 64; kk += 32) {
            short8 a0 = *(const short8*)&As[(mh + l16) * 72 + kk + quad * 8];
            short8 a1 = *(const short8*)&As[(mh + 16 + l16) * 72 + kk + quad * 8];
            short8 b0 = *(const short8*)&Ws[(nh + l16) * 72 + kk + quad * 8];
            short8 b1 = *(const short8*)&Ws[(nh + 16 + l16) * 72 + kk + quad * 8];
            acc00 = __builtin_amdgcn_mfma_f32_16x16x32_bf16(a0, b0, acc00, 0, 0, 0);
            acc01 = __builtin_amdgcn_mfma_f32_16x16x32_bf16(a0, b1, acc01, 0, 0, 0);
            acc10 = __builtin_amdgcn_mfma_f32_16x16x32_bf16(a1, b0, acc10, 0, 0, 0);
            acc11 = __builtin_amdgcn_mfma_f32_16x16x32_bf16(a1, b1, acc11, 0, 0, 0);
        }
        __syncthreads();
    }

    const int col0 = bn + nh + l16;
    const int col1 = col0 + 16;
    float bias0 = bias ? bias[col0] : 0.f;
    float bias1 = bias ? bias[col1] : 0.f;

    f32x4 accs[2][2] = {{acc00, acc01}, {acc10, acc11}};
    #pragma unroll
    for (int mt = 0; mt < 2; ++mt) {
        #pragma unroll
        for (int r = 0; r < 4; ++r) {
            int row = bm + mh + mt * 16 + quad * 4 + r;
            size_t rowoff = (size_t)row * ldc;
            float v0 = accs[mt][0][r] + bias0;
            float v1 = accs[mt][1][r] + bias1;
            if (EPI == 1) { v0 = __expf(2.f * v0); v1 = __expf(2.f * v1); }
            if (EPI == 2) {
                ushort_t* C = (ushort_t*)Cv;
                C[rowoff + col0] = f2bf(v0);
                C[rowoff + col1] = f2bf(v1);
            } else {
                float* C = (float*)Cv;
                C[rowoff + col0] = v0;
                C[rowoff + col1] = v1;
            }
        }
    }
}

// ---------------------------------------------------------------------------
// K1: fused front (640 GEMM blocks)
// [0,64)    Ew = exp(2*(inp@Wq^T + bq))
// [64,320)  Eu = exp(2*(ctx@Wc^T))
// [320,576) GT[b][n,s] = sum_d WL[n,d]*ctx[b][s,d]  (bf16)
// [576,640) Y0 = inp@WR^T + bout
// ---------------------------------------------------------------------------
__global__ __launch_bounds__(256) void fused_front(
    const float* __restrict__ inp, const float* __restrict__ ctx,
    const float* __restrict__ Wq, const float* __restrict__ bq,
    const float* __restrict__ Wc, const float* __restrict__ Wout,
    const float* __restrict__ bout,
    float* __restrict__ Ew, float* __restrict__ Eu, float* __restrict__ Y0,
    ushort_t* __restrict__ GT)
{
    __shared__ ushort_t As[64 * 72];
    __shared__ ushort_t Ws[64 * 72];
    const int bid = blockIdx.x;

    if (bid < 64) {
        gemm_body<false, false, 1>(As, Ws, inp, Wq, bq, Ew,
                                   512, 512, 512, 512, (bid & 7) * 64, (bid >> 3) * 64);
    } else if (bid < 320) {
        int i = bid - 64;
        gemm_body<false, false, 1>(As, Ws, ctx, Wc, nullptr, Eu,
                                   512, 512, 512, 512, (i & 31) * 64, (i >> 5) * 64);
    } else if (bid < 576) {
        int i = bid - 320;
        int b = i >> 6, j = i & 63;
        gemm_body<false, false, 2>(As, Ws, Wout, ctx + (size_t)b * 262144, nullptr,
                                   GT + (size_t)b * 262144,
                                   512, 1024, 512, 512, (j & 7) * 64, (j >> 3) * 64);
    } else {
        int i = bid - 576;
        gemm_body<false, false, 0>(As, Ws, inp, Wout + 512, bout, Y0,
                                   512, 512, 1024, 512, (i & 7) * 64, (i >> 3) * 64);
    }
}

// ---------------------------------------------------------------------------
// K2: one (b,t) row per block. 256 threads = 4 waves.
//  A: wave w computes scores for s in [w*128, w*128+128):
//       score[s] = V - 2*sum_d v[d]/(1 + Ew[row,d]*Eu[b,s,d])
//  B: block softmax over score[512]; write alignv row (fp32) + Pf to LDS
//  C: wave w computes attn[row][n], n in [w*128, w*128+128):
//       sum_s Pf[s]*GT[b][n][s] + Y0[row][n]   (shuffle-reduced)
// ---------------------------------------------------------------------------
__global__ __launch_bounds__(256) void fused_align(
    const float* __restrict__ Ew, const float* __restrict__ Eu,
    const float* __restrict__ v, const ushort_t* __restrict__ GT,
    const float* __restrict__ Y0, float* __restrict__ attn,
    float* __restrict__ alignv)
{
    __shared__ float sc[512];
    __shared__ float Pf[512];
    __shared__ float redm[4];
    __shared__ float reds[4];

    const int tid = threadIdx.x;
    const int lane = tid & 63, w = tid >> 6;
    const int b = blockIdx.x >> 7;
    const int row = blockIdx.x;               // b*128 + t

    // --- Phase A: scores ---------------------------------------------------
    const float* EwRow = Ew + ((size_t)row << 9);
    float Ewr[8], vr[8];
    float vloc = 0.f;
    #pragma unroll
    for (int c = 0; c < 8; ++c) {
        Ewr[c] = EwRow[c * 64 + lane];
        vr[c]  = v[c * 64 + lane];
        vloc  += vr[c];
    }
    float V = vloc;
    #pragma unroll
    for (int off = 32; off; off >>= 1) V += __shfl_xor(V, off, 64);

    const float* Eub = Eu + (((size_t)b) << 18);   // b*512*512
    for (int si = 0; si < 128; si += 2) {
        int s0 = w * 128 + si;
        const float* u0 = Eub + ((size_t)s0 << 9);
        const float* u1 = u0 + 512;
        float a0 = 0.f, a1 = 0.f;
        #pragma unroll
        for (int c = 0; c < 8; ++c) {
            float x0 = u0[c * 64 + lane];
            float x1 = u1[c * 64 + lane];
            float d0 = fmaf(Ewr[c], x0, 1.f);
            float d1 = fmaf(Ewr[c], x1, 1.f);
            float r0 = __builtin_amdgcn_rcpf(d0);
            float r1 = __builtin_amdgcn_rcpf(d1);
            a0 = fmaf(vr[c], r0, a0);
            a1 = fmaf(vr[c], r1, a1);
        }
        #pragma unroll
        for (int off = 32; off; off >>= 1) {
            a0 += __shfl_xor(a0, off, 64);
            a1 += __shfl_xor(a1, off, 64);
        }
        if (lane == 0) sc[s0]     = fmaf(-2.f, a0, V);
        if (lane == 1) sc[s0 + 1] = fmaf(-2.f, a1, V);
    }
    __syncthreads();

    // --- Phase B: softmax --------------------------------------------------
    float x0 = sc[tid];
    float x1 = sc[tid + 256];
    float m = fmaxf(x0, x1);
    #pragma unroll
    for (int off = 32; off; off >>= 1) m = fmaxf(m, __shfl_xor(m, off, 64));
    if (lane == 0) redm[w] = m;
    __syncthreads();
    m = fmaxf(fmaxf(redm[0], redm[1]), fmaxf(redm[2], redm[3]));
    float e0 = __expf(x0 - m);
    float e1 = __expf(x1 - m);
    float s = e0 + e1;
    #pragma unroll
    for (int off = 32; off; off >>= 1) s += __shfl_xor(s, off, 64);
    if (lane == 0) reds[w] = s;
    __syncthreads();
    s = reds[0] + reds[1] + reds[2] + reds[3];
    float rinv = 1.0f / s;
    float p0 = e0 * rinv, p1 = e1 * rinv;
    float* arow = alignv + ((size_t)row << 9);
    arow[tid] = p0;
    arow[tid + 256] = p1;
    Pf[tid] = p0;
    Pf[tid + 256] = p1;
    __syncthreads();

    // --- Phase C: attn row = P @ GT^T + Y0 ---------------------------------
    const unsigned* GTb = (const unsigned*)(GT + (((size_t)b) << 18));
    const float* yrow = Y0 + ((size_t)row << 9);
    float* orow = attn + ((size_t)row << 9);
    for (int ni = 0; ni < 128; ni += 2) {
        int n0 = w * 128 + ni;
        const unsigned* g0 = GTb + (n0 << 8);   // 256 uint per row
        const unsigned* g1 = g0 + 256;
        float a0 = 0.f, a1 = 0.f;
        #pragma unroll
        for (int c = 0; c < 4; ++c) {
            unsigned u0 = g0[c * 64 + lane];
            unsigned u1 = g1[c * 64 + lane];
            float2 pp = *(const float2*)&Pf[c * 128 + lane * 2];
            float g0lo = bfu_as_f(u0 << 16), g0hi = bfu_as_f(u0 & 0xffff0000u);
            float g1lo = bfu_as_f(u1 << 16), g1hi = bfu_as_f(u1 & 0xffff0000u);
            a0 = fmaf(pp.x, g0lo, a0); a0 = fmaf(pp.y, g0hi, a0);
            a1 = fmaf(pp.x, g1lo, a1); a1 = fmaf(pp.y, g1hi, a1);
        }
        #pragma unroll
        for (int off = 32; off; off >>= 1) {
            a0 += __shfl_xor(a0, off, 64);
            a1 += __shfl_xor(a1, off, 64);
        }
        if (lane == 0) orow[n0]     = a0 + yrow[n0];
        if (lane == 1) orow[n0 + 1] = a1 + yrow[n0 + 1];
    }
}

// ---------------------------------------------------------------------------
extern "C" void kernel_launch(void* const* d_in, const int* in_sizes, int n_in,
                              void* d_out, int out_size, void* d_ws, size_t ws_size,
                              hipStream_t stream)
{
    const float* inp  = (const float*)d_in[0];   // (4,128,512)
    const float* ctx  = (const float*)d_in[1];   // (4,512,512)
    const float* Wq   = (const float*)d_in[2];   // (512,512)
    const float* bq   = (const float*)d_in[3];   // (512)
    const float* Wc   = (const float*)d_in[4];   // (512,512)
    const float* v    = (const float*)d_in[5];   // (512)
    const float* Wout = (const float*)d_in[6];   // (512,1024)
    const float* bout = (const float*)d_in[7];   // (512)

    float* out    = (float*)d_out;
    float* attn   = out;              // 262144 floats
    float* alignv = out + 262144;     // 262144 floats

    float* ws = (float*)d_ws;
    float* Ew   = ws;                          // 262144 f
    float* Eu   = ws + 262144;                 // 1048576 f
    float* Y0   = ws + 1310720;                // 262144 f
    ushort_t* GT = (ushort_t*)(ws + 1572864);  // 4 x 262144 u16

    fused_front<<<dim3(640), 256, 0, stream>>>(inp, ctx, Wq, bq, Wc, Wout, bout,
                                               Ew, Eu, Y0, GT);
    fused_align<<<dim3(512), 256, 0, stream>>>(Ew, Eu, v, GT, Y0, attn, alignv);
}

// Round 9
// 121.444 us; speedup vs baseline: 2.4238x; 1.4867x over previous
//
#include <hip/hip_runtime.h>
#include <hip/hip_bf16.h>
#include <math.h>

// B=4, T=128, S=512, D=512. Outputs: attn_h (4,128,512) then align (4,128,512), fp32.
// 4-kernel pipeline (R4/R5 hybrid):
//   K1 fused_front (640): Ew=exp(2(inp@Wq^T+bq)), Eu=exp(2 ctx@Wc^T),
//      GT[b]=(WL@ctx_b^T) bf16, Y0=inp@WR^T+bout
//   K2 align (2048): Sraw[b,t,s] = V - 2*sum_d v[d]/(1+Ew*Eu)  (== sum v*tanh)
//      4 t/wave for load amortization + ILP
//   K3 softmax (512): alignv (fp32, d_out) + P_bf (bf16, ws), exp once/element
//   K4 gemm_att (64): attn = P_bf @ GT^T + Y0   (MFMA, K=512)

typedef __attribute__((ext_vector_type(8))) short short8;
typedef __attribute__((ext_vector_type(4))) float f32x4;
typedef unsigned short ushort_t;

static __device__ __forceinline__ unsigned short f2bf(float x) {
    union { __hip_bfloat16 h; unsigned short u; } c;
    c.h = __float2bfloat16(x);
    return c.u;
}
static __device__ __forceinline__ int bf2x(float lo, float hi) {
    return (int)(((unsigned)f2bf(hi) << 16) | (unsigned)f2bf(lo));
}

template<bool BF>
static __device__ __forceinline__ void load16(const void* base, size_t elemoff,
                                              int4& r0, int4& r1) {
    if (BF) {
        const int4* p = (const int4*)((const ushort_t*)base + elemoff);
        r0 = p[0]; r1 = p[1];
    } else {
        const float4* p = (const float4*)((const float*)base + elemoff);
        float4 a = p[0], b = p[1], c = p[2], d = p[3];
        r0.x = bf2x(a.x, a.y); r0.y = bf2x(a.z, a.w);
        r0.z = bf2x(b.x, b.y); r0.w = bf2x(b.z, b.w);
        r1.x = bf2x(c.x, c.y); r1.y = bf2x(c.z, c.w);
        r1.z = bf2x(d.x, d.y); r1.w = bf2x(d.z, d.w);
    }
}

// ---------------------------------------------------------------------------
// MFMA NT GEMM tile: C[m,n] = sum_k A[m,k]*W[n,k] (+bias). 64x64 tile, BK=64,
// 256 thr = 4 waves (2x2 of 32x32), 2x2 MFMA 16x16x32 per 32-K step.
// LDS rows padded to 72 bf16 (<=2-way bank aliasing on b128 = free).
// EPI: 0 fp32+bias; 1 fp32 exp(2*(x+bias)); 2 bf16; 3 fp32 + partial[].
// ---------------------------------------------------------------------------
template<bool A_BF, bool W_BF, int EPI>
static __device__ __forceinline__ void gemm_body(
    ushort_t* As, ushort_t* Ws,
    const void* A, const void* W, const float* bias, const float* partial,
    void* Cv, int K, int lda, int ldw, int ldc, int bm, int bn)
{
    const int tid = threadIdx.x;
    const int wave = tid >> 6, lane = tid & 63;
    const int mh = (wave & 1) * 32, nh = (wave >> 1) * 32;
    const int quad = lane >> 4, l16 = lane & 15;
    const int srow = tid >> 2, schunk = tid & 3;

    const size_t aoff = (size_t)(bm + srow) * lda + schunk * 16;
    const size_t woff = (size_t)(bn + srow) * ldw + schunk * 16;
    int4* AsW = (int4*)&As[srow * 72 + schunk * 16];
    int4* WsW = (int4*)&Ws[srow * 72 + schunk * 16];

    f32x4 acc00 = {0.f, 0.f, 0.f, 0.f}, acc01 = acc00, acc10 = acc00, acc11 = acc00;

    int4 a0r, a1r, w0r, w1r;
    load16<A_BF>(A, aoff, a0r, a1r);
    load16<W_BF>(W, woff, w0r, w1r);

    for (int k0 = 0; k0 < K; k0 += 64) {
        AsW[0] = a0r; AsW[1] = a1r;
        WsW[0] = w0r; WsW[1] = w1r;
        __syncthreads();
        if (k0 + 64 < K) {
            load16<A_BF>(A, aoff + k0 + 64, a0r, a1r);
            load16<W_BF>(W, woff + k0 + 64, w0r, w1r);
        }
        #pragma unroll
        for (int kk = 0; kk < 64; kk += 32) {
            short8 a0 = *(const short8*)&As[(mh + l16) * 72 + kk + quad * 8];
            short8 a1 = *(const short8*)&As[(mh + 16 + l16) * 72 + kk + quad * 8];
            short8 b0 = *(const short8*)&Ws[(nh + l16) * 72 + kk + quad * 8];
            short8 b1 = *(const short8*)&Ws[(nh + 16 + l16) * 72 + kk + quad * 8];
            acc00 = __builtin_amdgcn_mfma_f32_16x16x32_bf16(a0, b0, acc00, 0, 0, 0);
            acc01 = __builtin_amdgcn_mfma_f32_16x16x32_bf16(a0, b1, acc01, 0, 0, 0);
            acc10 = __builtin_amdgcn_mfma_f32_16x16x32_bf16(a1, b0, acc10, 0, 0, 0);
            acc11 = __builtin_amdgcn_mfma_f32_16x16x32_bf16(a1, b1, acc11, 0, 0, 0);
        }
        __syncthreads();
    }

    const int col0 = bn + nh + l16;
    const int col1 = col0 + 16;
    float bias0 = bias ? bias[col0] : 0.f;
    float bias1 = bias ? bias[col1] : 0.f;

    f32x4 accs[2][2] = {{acc00, acc01}, {acc10, acc11}};
    #pragma unroll
    for (int mt = 0; mt < 2; ++mt) {
        #pragma unroll
        for (int r = 0; r < 4; ++r) {
            int row = bm + mh + mt * 16 + quad * 4 + r;
            size_t rowoff = (size_t)row * ldc;
            float v0 = accs[mt][0][r] + bias0;
            float v1 = accs[mt][1][r] + bias1;
            if (EPI == 1) { v0 = __expf(2.f * v0); v1 = __expf(2.f * v1); }
            if (EPI == 3) { v0 += partial[rowoff + col0]; v1 += partial[rowoff + col1]; }
            if (EPI == 2) {
                ushort_t* C = (ushort_t*)Cv;
                C[rowoff + col0] = f2bf(v0);
                C[rowoff + col1] = f2bf(v1);
            } else {
                float* C = (float*)Cv;
                C[rowoff + col0] = v0;
                C[rowoff + col1] = v1;
            }
        }
    }
}

// ---------------------------------------------------------------------------
// K1: fused front (640 GEMM blocks)
// [0,64)    Ew = exp(2*(inp@Wq^T + bq))
// [64,320)  Eu = exp(2*(ctx@Wc^T))
// [320,576) GT[b][n,s] = sum_d WL[n,d]*ctx[b][s,d]  (bf16)
// [576,640) Y0 = inp@WR^T + bout
// ---------------------------------------------------------------------------
__global__ __launch_bounds__(256) void fused_front(
    const float* __restrict__ inp, const float* __restrict__ ctx,
    const float* __restrict__ Wq, const float* __restrict__ bq,
    const float* __restrict__ Wc, const float* __restrict__ Wout,
    const float* __restrict__ bout,
    float* __restrict__ Ew, float* __restrict__ Eu, float* __restrict__ Y0,
    ushort_t* __restrict__ GT)
{
    __shared__ ushort_t As[64 * 72];
    __shared__ ushort_t Ws[64 * 72];
    const int bid = blockIdx.x;

    if (bid < 64) {
        gemm_body<false, false, 1>(As, Ws, inp, Wq, bq, nullptr, Ew,
                                   512, 512, 512, 512, (bid & 7) * 64, (bid >> 3) * 64);
    } else if (bid < 320) {
        int i = bid - 64;
        gemm_body<false, false, 1>(As, Ws, ctx, Wc, nullptr, nullptr, Eu,
                                   512, 512, 512, 512, (i & 31) * 64, (i >> 5) * 64);
    } else if (bid < 576) {
        int i = bid - 320;
        int b = i >> 6, j = i & 63;
        gemm_body<false, false, 2>(As, Ws, Wout, ctx + (size_t)b * 262144, nullptr,
                                   nullptr, GT + (size_t)b * 262144,
                                   512, 1024, 512, 512, (j & 7) * 64, (j >> 3) * 64);
    } else {
        int i = bid - 576;
        gemm_body<false, false, 0>(As, Ws, inp, Wout + 512, bout, nullptr, Y0,
                                   512, 512, 1024, 512, (i & 7) * 64, (i >> 3) * 64);
    }
}

// ---------------------------------------------------------------------------
// K2: Sraw[b,t,s] = V - 2*sum_d v[d]/(1 + Ew[b,t,d]*Eu[b,s,d]),  V = sum v[d]
// Wave w: 4 t's (t0 = by*16 + w*4), 8 s's. Grid (64, 8, 4) = 2048 blocks.
// k across lanes; each Eu load feeds 4 t-accumulators (load amortization+ILP).
// ---------------------------------------------------------------------------
__global__ __launch_bounds__(256) void align_kernel(
    const float* __restrict__ Ew, const float* __restrict__ Eu,
    const float* __restrict__ v, float* __restrict__ out)
{
    const int lane = threadIdx.x & 63, wave = threadIdx.x >> 6;
    const int b = blockIdx.z;
    const int t0 = blockIdx.y * 16 + wave * 4;
    const int s0 = blockIdx.x * 8;

    const float* wp = Ew + (((size_t)(b * 128 + t0)) << 9);
    const float* up = Eu + (((size_t)(b * 512 + s0)) << 9);

    float acc[4][8];
    #pragma unroll
    for (int i = 0; i < 4; ++i)
        #pragma unroll
        for (int j = 0; j < 8; ++j) acc[i][j] = 0.f;
    float vsum = 0.f;

    for (int k0 = 0; k0 < 512; k0 += 64) {
        float vk = v[k0 + lane];
        vsum += vk;
        float w0 = wp[k0 + lane];
        float w1 = wp[512 + k0 + lane];
        float w2 = wp[1024 + k0 + lane];
        float w3 = wp[1536 + k0 + lane];
        #pragma unroll
        for (int j = 0; j < 8; ++j) {
            float u = up[((size_t)j << 9) + k0 + lane];
            float d0 = fmaf(w0, u, 1.f);
            float d1 = fmaf(w1, u, 1.f);
            float d2 = fmaf(w2, u, 1.f);
            float d3 = fmaf(w3, u, 1.f);
            float r0 = __builtin_amdgcn_rcpf(d0);
            float r1 = __builtin_amdgcn_rcpf(d1);
            float r2 = __builtin_amdgcn_rcpf(d2);
            float r3 = __builtin_amdgcn_rcpf(d3);
            acc[0][j] = fmaf(vk, r0, acc[0][j]);
            acc[1][j] = fmaf(vk, r1, acc[1][j]);
            acc[2][j] = fmaf(vk, r2, acc[2][j]);
            acc[3][j] = fmaf(vk, r3, acc[3][j]);
        }
    }

    float V = vsum;
    #pragma unroll
    for (int off = 32; off; off >>= 1) V += __shfl_xor(V, off, 64);

    float r0 = 0.f, r1 = 0.f, r2 = 0.f, r3 = 0.f;
    #pragma unroll
    for (int j = 0; j < 8; ++j) {
        float a0 = acc[0][j], a1 = acc[1][j], a2 = acc[2][j], a3 = acc[3][j];
        #pragma unroll
        for (int off = 32; off; off >>= 1) {
            a0 += __shfl_xor(a0, off, 64);
            a1 += __shfl_xor(a1, off, 64);
            a2 += __shfl_xor(a2, off, 64);
            a3 += __shfl_xor(a3, off, 64);
        }
        if (lane == j) {
            r0 = fmaf(-2.f, a0, V);
            r1 = fmaf(-2.f, a1, V);
            r2 = fmaf(-2.f, a2, V);
            r3 = fmaf(-2.f, a3, V);
        }
    }
    if (lane < 8) {
        size_t o = (((size_t)(b * 128 + t0)) << 9) + s0 + lane;
        out[o] = r0;
        out[o + 512] = r1;
        out[o + 1024] = r2;
        out[o + 1536] = r3;
    }
}

// ---------------------------------------------------------------------------
// K3: softmax over rows of 512. Reads Sraw, writes fp32 alignv + bf16 P.
// ---------------------------------------------------------------------------
__global__ __launch_bounds__(256) void softmax_512(
    const float* __restrict__ Sraw, float* __restrict__ alignv,
    ushort_t* __restrict__ pbf)
{
    const int row = blockIdx.x;
    const float* p = Sraw + ((size_t)row << 9);
    float* a = alignv + ((size_t)row << 9);
    ushort_t* q = pbf + ((size_t)row << 9);
    const int tid = threadIdx.x;
    float x0 = p[tid];
    float x1 = p[tid + 256];

    float m = fmaxf(x0, x1);
    #pragma unroll
    for (int off = 32; off > 0; off >>= 1)
        m = fmaxf(m, __shfl_xor(m, off, 64));
    __shared__ float redm[4];
    __shared__ float reds[4];
    const int wave = tid >> 6;
    if ((tid & 63) == 0) redm[wave] = m;
    __syncthreads();
    m = fmaxf(fmaxf(redm[0], redm[1]), fmaxf(redm[2], redm[3]));

    float e0 = __expf(x0 - m);
    float e1 = __expf(x1 - m);
    float s = e0 + e1;
    #pragma unroll
    for (int off = 32; off > 0; off >>= 1)
        s += __shfl_xor(s, off, 64);
    if ((tid & 63) == 0) reds[wave] = s;
    __syncthreads();
    s = reds[0] + reds[1] + reds[2] + reds[3];
    float r = 1.0f / s;
    float p0 = e0 * r, p1 = e1 * r;
    a[tid] = p0;
    a[tid + 256] = p1;
    q[tid] = f2bf(p0);
    q[tid + 256] = f2bf(p1);
}

// ---------------------------------------------------------------------------
// K4: attn = P_bf @ GT^T + Y0. Per-batch M=128, N=512, K=512. Grid (2,8,4).
// ---------------------------------------------------------------------------
__global__ __launch_bounds__(256) void gemm_att(
    const ushort_t* __restrict__ P, const ushort_t* __restrict__ GT,
    const float* __restrict__ Y0, float* __restrict__ attn)
{
    __shared__ ushort_t As[64 * 72];
    __shared__ ushort_t Ws[64 * 72];
    const int b = blockIdx.z;
    gemm_body<true, true, 3>(As, Ws,
                             P + (size_t)b * 65536, GT + (size_t)b * 262144,
                             nullptr, Y0 + (size_t)b * 65536,
                             attn + (size_t)b * 65536,
                             512, 512, 512, 512, blockIdx.x * 64, blockIdx.y * 64);
}

// ---------------------------------------------------------------------------
extern "C" void kernel_launch(void* const* d_in, const int* in_sizes, int n_in,
                              void* d_out, int out_size, void* d_ws, size_t ws_size,
                              hipStream_t stream)
{
    const float* inp  = (const float*)d_in[0];   // (4,128,512)
    const float* ctx  = (const float*)d_in[1];   // (4,512,512)
    const float* Wq   = (const float*)d_in[2];   // (512,512)
    const float* bq   = (const float*)d_in[3];   // (512)
    const float* Wc   = (const float*)d_in[4];   // (512,512)
    const float* v    = (const float*)d_in[5];   // (512)
    const float* Wout = (const float*)d_in[6];   // (512,1024)
    const float* bout = (const float*)d_in[7];   // (512)

    float* out    = (float*)d_out;
    float* attn   = out;              // 262144 floats
    float* alignv = out + 262144;     // 262144 floats

    float* ws = (float*)d_ws;
    float* Ew   = ws;                          // 262144 f
    float* Eu   = ws + 262144;                 // 1048576 f
    float* Y0   = ws + 1310720;                // 262144 f
    float* Sraw = ws + 1572864;                // 262144 f
    ushort_t* GT   = (ushort_t*)(ws + 1835008); // 1048576 u16 (= 524288 f)
    ushort_t* P_bf = (ushort_t*)(ws + 2359296); // 262144 u16

    fused_front<<<dim3(640), 256, 0, stream>>>(inp, ctx, Wq, bq, Wc, Wout, bout,
                                               Ew, Eu, Y0, GT);
    align_kernel<<<dim3(64, 8, 4), 256, 0, stream>>>(Ew, Eu, v, Sraw);
    softmax_512<<<dim3(512), 256, 0, stream>>>(Sraw, alignv, P_bf);
    gemm_att<<<dim3(2, 8, 4), 256, 0, stream>>>(P_bf, GT, Y0, attn);
}